// Round 3
// baseline (285.213 us; speedup 1.0000x reference)
//
#include <hip/hip_runtime.h>

#define NPTS 32768
#define BLOCK 256
#define SPT 8                             // source points per thread
#define NSLICE 32                         // target slices per direction
#define SLICE_PTS (NPTS / NSLICE)         // 1024
#define SRC_PER_BLOCK (BLOCK * SPT)       // 2048
#define SRC_CHUNKS (NPTS / SRC_PER_BLOCK) // 16
// grid = 2 * SRC_CHUNKS * NSLICE = 1024 blocks

// Pass 1: block = (dir, source-chunk of 2048, target-slice of 1024).
// Track M = max_t (2 s.t - |t|^2); min dist = |s|^2 - M.
// Targets are wave-uniform -> scalar loads into SGPRs (no LDS at all).
// Inner per 2 targets: 6 VALU for |t|^2 (uniform, VGPR) + 8 pts x (6 fma + max3).
__global__ __launch_bounds__(BLOCK, 4)
void chamfer_pass1(const float* __restrict__ pred,
                   const float* __restrict__ targ,
                   unsigned int* __restrict__ mins) {
    int b = blockIdx.x;
    int dir = b >> 9;            // 0: pred->target, 1: target->pred
    int rem = b & 511;
    int slice = rem >> 4;        // 0..31
    int chunk = rem & 15;        // 0..15

    const float* src = dir ? targ : pred;
    const float* tgt = dir ? pred : targ;
    unsigned int* outm = mins + dir * NPTS;

    // load 8 source points; keep s2 = 2*s in registers
    float s2x[SPT], s2y[SPT], s2z[SPT], m[SPT];
    int i_base = chunk * SRC_PER_BLOCK + threadIdx.x;
    #pragma unroll
    for (int p = 0; p < SPT; ++p) {
        int i = i_base + p * BLOCK;
        s2x[p] = 2.0f * src[3*i+0];
        s2y[p] = 2.0f * src[3*i+1];
        s2z[p] = 2.0f * src[3*i+2];
        m[p] = -3.4e38f;
    }

    // uniform base pointer for this block's target slice
    const float* tb = tgt + 3 * slice * SLICE_PTS;

    #pragma unroll 8
    for (int j = 0; j < SLICE_PTS; j += 2) {
        // uniform scalar loads -> SGPRs (compiler merges into s_load_dwordx*)
        float tax = tb[3*j+0], tay = tb[3*j+1], taz = tb[3*j+2];
        float tbx = tb[3*j+3], tby = tb[3*j+4], tbz = tb[3*j+5];
        // |t|^2 in VALU (uniform value lives in a VGPR -> frees SGPR-read slot)
        float tta = fmaf(tax, tax, fmaf(tay, tay, taz * taz));
        float ttb = fmaf(tbx, tbx, fmaf(tby, tby, tbz * tbz));
        #pragma unroll
        for (int p = 0; p < SPT; ++p) {
            float ra = fmaf(s2x[p], tax, fmaf(s2y[p], tay, fmaf(s2z[p], taz, -tta)));
            float rb = fmaf(s2x[p], tbx, fmaf(s2y[p], tby, fmaf(s2z[p], tbz, -ttb)));
            m[p] = fmaxf(m[p], fmaxf(ra, rb));   // -> v_max3_f32
        }
    }

    #pragma unroll
    for (int p = 0; p < SPT; ++p) {
        int i = i_base + p * BLOCK;
        // |s|^2 = 0.25 * |s2|^2
        float dd = fmaf(s2x[p], s2x[p], fmaf(s2y[p], s2y[p], s2z[p]*s2z[p]));
        float d = fmaxf(fmaf(0.25f, dd, -m[p]), 0.0f);  // exact distance >= 0
        atomicMin(&outm[i], __float_as_uint(d));        // non-neg float: uint cmp ok
    }
}

// Pass 2: sum all 65536 per-point mins; out = sum / 32768 (= mean1 + mean2).
__global__ __launch_bounds__(256)
void chamfer_pass2(const unsigned int* __restrict__ mins,
                   float* __restrict__ out) {
    float sum = 0.0f;
    for (int i = blockIdx.x * blockDim.x + threadIdx.x; i < 2 * NPTS;
         i += gridDim.x * blockDim.x)
        sum += __uint_as_float(mins[i]);
    #pragma unroll
    for (int off = 32; off > 0; off >>= 1)
        sum += __shfl_down(sum, off, 64);
    __shared__ float wsum[4];
    int lane = threadIdx.x & 63, wave = threadIdx.x >> 6;
    if (lane == 0) wsum[wave] = sum;
    __syncthreads();
    if (threadIdx.x == 0) {
        float s = wsum[0] + wsum[1] + wsum[2] + wsum[3];
        atomicAdd(out, s * (1.0f / NPTS));
    }
}

extern "C" void kernel_launch(void* const* d_in, const int* in_sizes, int n_in,
                              void* d_out, int out_size, void* d_ws, size_t ws_size,
                              hipStream_t stream) {
    const float* pred = (const float*)d_in[0];
    const float* targ = (const float*)d_in[1];
    float* out = (float*)d_out;
    unsigned int* mins = (unsigned int*)d_ws;

    // sentinel 0x7F7F7F7F == 3.39e38f in every ws float
    hipMemsetAsync(d_ws, 0x7F, 2 * NPTS * sizeof(float), stream);
    hipMemsetAsync(d_out, 0, sizeof(float), stream);

    chamfer_pass1<<<2 * SRC_CHUNKS * NSLICE, BLOCK, 0, stream>>>(pred, targ, mins);
    chamfer_pass2<<<64, 256, 0, stream>>>(mins, out);
}

// Round 4
// 211.824 us; speedup vs baseline: 1.3465x; 1.3465x over previous
//
#include <hip/hip_runtime.h>

#define NPTS 32768
#define BLOCK 256
#define SPT 16                            // source points per thread
#define NSLICE 64                         // target slices per direction
#define SLICE_PTS (NPTS / NSLICE)         // 512
#define SRC_PER_BLOCK (BLOCK * SPT)       // 4096
#define SRC_CHUNKS (NPTS / SRC_PER_BLOCK) // 8
// grid = 2 * SRC_CHUNKS * NSLICE = 1024 blocks -> 4 blocks/CU, 16 waves/CU

// Pass 1: block = (dir, source-chunk of 4096, target-slice of 512).
// min_t |s-t|^2 = |s|^2 - 2 * max_t (s.t - |t|^2/2); qh = -|t|^2/2 staged in LDS.
// Per j-step: 2 broadcast ds_read_b128 feed 16 pts x (6 fma + 1 max3) = 112 VALU.
__global__ __launch_bounds__(BLOCK, 4)
void chamfer_pass1(const float* __restrict__ pred,
                   const float* __restrict__ targ,
                   unsigned int* __restrict__ mins) {
    __shared__ float4 sh[SLICE_PTS + 2];   // +2: prefetch overrun pad (never consumed)

    int b = blockIdx.x;
    int dir = b >> 9;              // 0: pred->target, 1: target->pred
    int rem = b & 511;
    int slice = rem >> 3;          // 0..63
    int chunk = rem & 7;           // 0..7

    const float* src = dir ? targ : pred;
    const float* tgt = dir ? pred : targ;
    unsigned int* outm = mins + dir * NPTS;

    // stage the target slice as {x, y, z, -|t|^2/2}
    int slice_base = slice * SLICE_PTS;
    #pragma unroll
    for (int k = 0; k < SLICE_PTS / BLOCK; ++k) {
        int j = threadIdx.x + k * BLOCK;
        int g = slice_base + j;
        float x = tgt[3*g+0], y = tgt[3*g+1], z = tgt[3*g+2];
        sh[j] = make_float4(x, y, z, -0.5f * (x*x + y*y + z*z));
    }

    // load 16 source points into registers
    float sx[SPT], sy[SPT], sz[SPT], m[SPT];
    int i_base = chunk * SRC_PER_BLOCK + threadIdx.x;
    #pragma unroll
    for (int p = 0; p < SPT; ++p) {
        int i = i_base + p * BLOCK;
        sx[p] = src[3*i+0]; sy[p] = src[3*i+1]; sz[p] = src[3*i+2];
        m[p] = -3.4e38f;
    }
    __syncthreads();

    // software-pipelined: prefetch next target pair while computing current
    float4 ca = sh[0], cb = sh[1];
    #pragma unroll 4
    for (int j = 0; j < SLICE_PTS; j += 2) {
        float4 na = sh[j+2];       // pad makes last-iter read safe
        float4 nb = sh[j+3];
        #pragma unroll
        for (int p = 0; p < SPT; ++p) {
            float ra = fmaf(sx[p], ca.x, fmaf(sy[p], ca.y, fmaf(sz[p], ca.z, ca.w)));
            float rb = fmaf(sx[p], cb.x, fmaf(sy[p], cb.y, fmaf(sz[p], cb.z, cb.w)));
            m[p] = fmaxf(m[p], fmaxf(ra, rb));   // -> v_max3_f32
        }
        ca = na; cb = nb;
    }

    #pragma unroll
    for (int p = 0; p < SPT; ++p) {
        int i = i_base + p * BLOCK;
        float q = fmaf(sx[p], sx[p], fmaf(sy[p], sy[p], sz[p]*sz[p]));
        float d = fmaxf(fmaf(-2.0f, m[p], q), 0.0f);  // exact distance >= 0
        atomicMin(&outm[i], __float_as_uint(d));      // non-neg float: uint cmp ok
    }
}

// Pass 2: sum all 65536 per-point mins; out = sum / 32768 (= mean1 + mean2).
__global__ __launch_bounds__(256)
void chamfer_pass2(const unsigned int* __restrict__ mins,
                   float* __restrict__ out) {
    float sum = 0.0f;
    for (int i = blockIdx.x * blockDim.x + threadIdx.x; i < 2 * NPTS;
         i += gridDim.x * blockDim.x)
        sum += __uint_as_float(mins[i]);
    #pragma unroll
    for (int off = 32; off > 0; off >>= 1)
        sum += __shfl_down(sum, off, 64);
    __shared__ float wsum[4];
    int lane = threadIdx.x & 63, wave = threadIdx.x >> 6;
    if (lane == 0) wsum[wave] = sum;
    __syncthreads();
    if (threadIdx.x == 0) {
        float s = wsum[0] + wsum[1] + wsum[2] + wsum[3];
        atomicAdd(out, s * (1.0f / NPTS));
    }
}

extern "C" void kernel_launch(void* const* d_in, const int* in_sizes, int n_in,
                              void* d_out, int out_size, void* d_ws, size_t ws_size,
                              hipStream_t stream) {
    const float* pred = (const float*)d_in[0];
    const float* targ = (const float*)d_in[1];
    float* out = (float*)d_out;
    unsigned int* mins = (unsigned int*)d_ws;

    // sentinel 0x7F7F7F7F == 3.39e38f in every ws float
    hipMemsetAsync(d_ws, 0x7F, 2 * NPTS * sizeof(float), stream);
    hipMemsetAsync(d_out, 0, sizeof(float), stream);

    chamfer_pass1<<<2 * SRC_CHUNKS * NSLICE, BLOCK, 0, stream>>>(pred, targ, mins);
    chamfer_pass2<<<64, 256, 0, stream>>>(mins, out);
}